// Round 7
// baseline (163.565 us; speedup 1.0000x reference)
//
#include <hip/hip_runtime.h>
#include <hip/hip_bf16.h>
#include <stdint.h>
#include <stddef.h>

// ---------------------------------------------------------------------------
// TimeSeriesAttention: out = softmax((x Wq + bq)(x Wk + bk)^T / 16) (x Wv + bv)
// B=4, S=4096, H=256, fp32 in/out. bf16 MFMA path.
// v7: counted-vmcnt dual-barrier attn K-loop (loads stay in flight across
//     barriers; never drain to 0 mid-loop) + combine fused into attn epilogue
//     via device-scope counter (last sp-block normalizes). wt/proj from v6.
// ---------------------------------------------------------------------------

typedef __bf16 bf16;
typedef _Float16 f16;
typedef __attribute__((ext_vector_type(4))) __bf16 bf16x4;
typedef __attribute__((ext_vector_type(8))) __bf16 bf16x8;
typedef __attribute__((ext_vector_type(4))) float f32x4;
typedef __attribute__((ext_vector_type(4))) _Float16 f16x4;
typedef __attribute__((ext_vector_type(8))) _Float16 f16x8;

#define S_LEN 4096
#define HDIM  256
#define PSTRIDE ((size_t)16384 * 256)   // elems per fp16 partial buffer (8MB)

__device__ __forceinline__ f32x4 mfma16(bf16x8 a, bf16x8 b, f32x4 c) {
  return __builtin_amdgcn_mfma_f32_16x16x32_bf16(a, b, c, 0, 0, 0);
}

__device__ __forceinline__ void gld_lds16(const void* g, void* l) {
  __builtin_amdgcn_global_load_lds(
      (const __attribute__((address_space(1))) void*)g,
      (__attribute__((address_space(3))) void*)l, 16, 0, 0);
}

__device__ __forceinline__ float fast_exp2(float x) {
  float r;
  asm("v_exp_f32 %0, %1" : "=v"(r) : "v"(x));
  return r;
}

// barrier with counted vmcnt; pinned against IR/scheduler motion
#define BAR_VMCNT4() do { \
  asm volatile("s_waitcnt vmcnt(4)" ::: "memory"); \
  __builtin_amdgcn_s_barrier(); \
  asm volatile("" ::: "memory"); \
  __builtin_amdgcn_sched_barrier(0); } while (0)
#define BAR_VMCNT0() do { \
  asm volatile("s_waitcnt vmcnt(0)" ::: "memory"); \
  __builtin_amdgcn_s_barrier(); \
  asm volatile("" ::: "memory"); \
  __builtin_amdgcn_sched_barrier(0); } while (0)

// ---------------------------------------------------------------------------
// Kernel 1: WT_m[d][h] = (bf16) W_m[h][d].  192 blocks = 3 m x 64 (32x32) tiles.
// ---------------------------------------------------------------------------
__global__ __launch_bounds__(256) void wt_kernel(
    const float* __restrict__ Wq, const float* __restrict__ Wk,
    const float* __restrict__ Wv, bf16* __restrict__ WT) {
  __shared__ float tile[32][33];
  int bid = blockIdx.x;
  int m = bid >> 6;
  int t = bid & 63;
  int hb = (t >> 3) * 32;
  int db = (t & 7) * 32;
  const float* W = (m == 0) ? Wq : (m == 1) ? Wk : Wv;
  bf16* o = WT + m * 65536;
  int ty = threadIdx.x >> 3;
  int tx = threadIdx.x & 7;
  float4 v = *(const float4*)(W + (size_t)(hb + ty) * 256 + db + tx * 4);
  tile[ty][tx * 4 + 0] = v.x; tile[ty][tx * 4 + 1] = v.y;
  tile[ty][tx * 4 + 2] = v.z; tile[ty][tx * 4 + 3] = v.w;
  __syncthreads();
  bf16x4 h = {(bf16)tile[tx * 4 + 0][ty], (bf16)tile[tx * 4 + 1][ty],
              (bf16)tile[tx * 4 + 2][ty], (bf16)tile[tx * 4 + 3][ty]};
  *(bf16x4*)(o + (size_t)(db + ty) * 256 + hb + tx * 4) = h;
}

// ---------------------------------------------------------------------------
// Kernel 2: fused QKV projection (v6 structure, unchanged).
// ---------------------------------------------------------------------------
__global__ __launch_bounds__(256, 3) void proj_kernel(
    const float* __restrict__ x, const bf16* __restrict__ WT,
    const float* __restrict__ bq, const float* __restrict__ bk,
    const float* __restrict__ bv,
    bf16* __restrict__ Qb, char* __restrict__ KV) {
  __shared__ __align__(16) char smem[34816];
  int tid = threadIdx.x;
  int row0 = blockIdx.x * 64;
  int m = blockIdx.y;

#pragma unroll
  for (int i = 0; i < 16; ++i) {
    int c = i * 256 + tid;
    int r = c >> 6, c4 = c & 63;
    float4 v = *(const float4*)(x + (size_t)(row0 + r) * 256 + c4 * 4);
    bf16x4 b4 = {(bf16)v.x, (bf16)v.y, (bf16)v.z, (bf16)v.w};
    *(bf16x4*)(smem + r * 512 + ((c4 * 8) ^ ((r & 7) << 4))) = b4;
  }
  __syncthreads();

  int w = tid >> 6, lane = tid & 63, lg = lane >> 4, l15 = lane & 15;
  int ar = w * 16 + l15;
  int swz = (l15 & 7) << 4;
  bf16x8 af[8];
#pragma unroll
  for (int ks = 0; ks < 8; ++ks)
    af[ks] = *(const bf16x8*)(smem + ar * 512 + ((ks * 64 + lg * 16) ^ swz));
  __syncthreads();

  int b = row0 >> 12, t0 = (row0 & 4095) >> 5;
  const bf16* Wm = WT + m * 65536;
  const float* bias = (m == 0) ? bq : (m == 1) ? bk : bv;

#pragma unroll
  for (int i = 0; i < 4; ++i) {
    int c = w * 4 + i;
    gld_lds16(Wm + (c * 16 + l15) * 256 + lg * 8, smem + c * 1024 + lane * 16);
  }
  __syncthreads();

  f32x4 acc[16];
#pragma unroll
  for (int dt = 0; dt < 16; ++dt) acc[dt] = f32x4{0.f, 0.f, 0.f, 0.f};

  for (int ks = 0; ks < 8; ++ks) {
    const char* wb = smem + (ks & 1) * 16384;
    if (ks + 1 < 8) {
      char* wn = smem + ((ks + 1) & 1) * 16384;
#pragma unroll
      for (int i = 0; i < 4; ++i) {
        int c = w * 4 + i;
        gld_lds16(Wm + (c * 16 + l15) * 256 + (ks + 1) * 32 + lg * 8,
                  wn + c * 1024 + lane * 16);
      }
    }
    __builtin_amdgcn_s_setprio(1);
#pragma unroll
    for (int dt = 0; dt < 16; ++dt) {
      bf16x8 wf = *(const bf16x8*)(wb + dt * 1024 + lane * 16);
      acc[dt] = mfma16(af[ks], wf, acc[dt]);
    }
    __builtin_amdgcn_s_setprio(0);
    __syncthreads();
  }

  if (m == 0) {
#pragma unroll
    for (int dt = 0; dt < 16; ++dt) {
      float bb = bias[dt * 16 + l15];
#pragma unroll
      for (int rr = 0; rr < 4; ++rr) {
        int srow = row0 + w * 16 + 4 * lg + rr;
        Qb[(size_t)srow * 256 + dt * 16 + l15] = (bf16)(acc[dt][rr] + bb);
      }
    }
  } else if (m == 1) {
    bf16* sm16 = (bf16*)smem;
#pragma unroll
    for (int dt = 0; dt < 16; ++dt) {
      float bb = bias[dt * 16 + l15];
#pragma unroll
      for (int rr = 0; rr < 4; ++rr) {
        int sl = w * 16 + 4 * lg + rr;
        sm16[sl * 264 + dt * 16 + l15] = (bf16)(acc[dt][rr] + bb);
      }
    }
    __syncthreads();
    int tt = tid >> 7, c = (tid >> 3) & 15, j0 = (tid & 7) * 8;
    char* dst = KV + ((size_t)(b * 128 + t0 + tt)) * 32768 + c * 1024 + j0 * 16;
#pragma unroll
    for (int u = 0; u < 8; ++u) {
      int l = j0 + u;
      bf16x8 v8 = *(const bf16x8*)(sm16 + (tt * 32 + (c & 1) * 16 + (l & 15)) * 264
                                   + (c >> 1) * 32 + (l >> 4) * 8);
      *(bf16x8*)(dst + u * 16) = v8;
    }
  } else {
    bf16* smV = (bf16*)smem;
#pragma unroll
    for (int dt = 0; dt < 16; ++dt) {
      float bb = bias[dt * 16 + l15];
      bf16x4 h = {(bf16)(acc[dt][0] + bb), (bf16)(acc[dt][1] + bb),
                  (bf16)(acc[dt][2] + bb), (bf16)(acc[dt][3] + bb)};
      *(bf16x4*)(smV + (dt * 16 + l15) * 68 + w * 16 + 4 * lg) = h;
    }
    __syncthreads();
    int tt = tid >> 7, c = (tid >> 3) & 15, j0 = (tid & 7) * 8;
    char* dst = KV + ((size_t)(b * 128 + t0 + tt)) * 32768 + 16384
                + c * 1024 + j0 * 16;
#pragma unroll
    for (int u = 0; u < 8; ++u) {
      int l = j0 + u;
      const bf16* p = smV + (c * 16 + (l & 15)) * 68 + tt * 32 + 4 * (l >> 4);
      bf16x4 lo = *(const bf16x4*)p;
      bf16x4 hi = *(const bf16x4*)(p + 16);
      bf16x8 v8 = __builtin_shufflevector(lo, hi, 0, 1, 2, 3, 4, 5, 6, 7);
      *(bf16x8*)(dst + u * 16) = v8;
    }
  }
}

// ---------------------------------------------------------------------------
// Kernel 3: flash attention + fused combine.
//   4 waves x 32 q (QBLK=128), KVBLK=32, dual-barrier counted-vmcnt dbuf.
//   Last-arriving sp block per (b,qb) combines fp16 partials -> f32 out.
// ---------------------------------------------------------------------------
__global__ __launch_bounds__(256, 2) void attn_kernel(
    const bf16* __restrict__ Qb, const char* __restrict__ KV,
    f16* __restrict__ P, float* __restrict__ ml, float* __restrict__ out,
    int* __restrict__ cnt, int nsplit, int ntiles) {
  __shared__ __align__(16) char smem[65536];  // 2 bufs x (K 16KB | V 16KB)

  int id = blockIdx.x;
  int b, sp, qb;
  if (nsplit == 4)      { int g = id & 15; b = g & 3;  sp = g >> 2; qb = id >> 4; }
  else if (nsplit == 2) { int g = id & 7;  b = g >> 1; sp = g & 1;  qb = id >> 3; }
  else                  { b = id & 3; sp = 0; qb = id >> 2; }

  int tid = threadIdx.x;
  int w = tid >> 6, lane = tid & 63, lg = lane >> 4, l15 = lane & 15;

  const char* kvsrc = KV + ((size_t)(b * 128 + sp * ntiles)) * 32768;

  // Q fragments: q = qb*128 + w*32 + qs*16 + l15
  int qrow0 = b * S_LEN + qb * 128 + w * 32 + l15;
  bf16x8 qf[2][8];
#pragma unroll
  for (int qs = 0; qs < 2; ++qs) {
    const bf16* Qr = Qb + (size_t)(qrow0 + qs * 16) * HDIM;
#pragma unroll
    for (int ks = 0; ks < 8; ++ks)
      qf[qs][ks] = *(const bf16x8*)(Qr + ks * 32 + lg * 8);
  }

  f32x4 acc[2][16];
#pragma unroll
  for (int qs = 0; qs < 2; ++qs)
#pragma unroll
    for (int dt = 0; dt < 16; ++dt) acc[qs][dt] = f32x4{0.f, 0.f, 0.f, 0.f};
  float lsum[2] = {0.f, 0.f};
  const float C = 0.09016844005556021f;  // (1/16) * log2(e)

  // prologue: stage K(0)+V(0) -> buf 0, full drain once
#pragma unroll
  for (int i = 0; i < 8; ++i)
    gld_lds16(kvsrc + i * 4096 + tid * 16, smem + i * 4096 + tid * 16);
  BAR_VMCNT0();

  for (int t = 0; t < ntiles; ++t) {
    int cur = (t & 1) << 15;
    const char* kb = smem + cur;
    const char* vb = kb + 16384;
    const char* s2 = kvsrc + (size_t)(t + 1) * 32768;
    char* d2 = smem + (cur ^ 32768);
    bool pre = (t + 1 < ntiles);

    if (pre) {                      // issue K(t+1): stays in flight across B2
#pragma unroll
      for (int i = 0; i < 4; ++i)
        gld_lds16(s2 + i * 4096 + tid * 16, d2 + i * 4096 + tid * 16);
    }

    // S^T = K . Q^T (reads K(t); safe per B1 of t-1 / prologue)
    f32x4 st[2][2];
    st[0][0] = f32x4{0.f, 0.f, 0.f, 0.f}; st[0][1] = st[0][0];
    st[1][0] = st[0][0];                   st[1][1] = st[0][0];
    __builtin_amdgcn_s_setprio(1);
#pragma unroll
    for (int ks = 0; ks < 8; ++ks) {
      bf16x8 k0 = *(const bf16x8*)(kb + (ks * 2 + 0) * 1024 + lane * 16);
      bf16x8 k1 = *(const bf16x8*)(kb + (ks * 2 + 1) * 1024 + lane * 16);
      st[0][0] = mfma16(k0, qf[0][ks], st[0][0]);
      st[1][0] = mfma16(k0, qf[1][ks], st[1][0]);
      st[0][1] = mfma16(k1, qf[0][ks], st[0][1]);
      st[1][1] = mfma16(k1, qf[1][ks], st[1][1]);
    }
    __builtin_amdgcn_s_setprio(0);

    // B2: all waves' V(t) landed (K(t+1) may remain in flight)
    if (pre) BAR_VMCNT4(); else BAR_VMCNT0();

    if (pre) {                      // issue V(t+1): in flight across B1
#pragma unroll
      for (int i = 4; i < 8; ++i)
        gld_lds16(s2 + i * 4096 + tid * 16, d2 + i * 4096 + tid * 16);
    }

    // no-max softmax
    bf16x8 pf[2];
#pragma unroll
    for (int qs = 0; qs < 2; ++qs) {
      float ps = 0.f;
#pragma unroll
      for (int e = 0; e < 8; ++e) {
        float pv = fast_exp2(st[qs][e >> 2][e & 3] * C);
        ps += pv;
        pf[qs][e] = (bf16)pv;   // kv = 16*(e>>2) + 4*lg + (e&3)
      }
      lsum[qs] += ps;
    }

    // O^T += V^T . P^T (reads V(t); safe per B2)
    __builtin_amdgcn_s_setprio(1);
#pragma unroll
    for (int dt = 0; dt < 16; ++dt) {
      bf16x8 vf = *(const bf16x8*)(vb + dt * 1024 + lane * 16);
      acc[0][dt] = mfma16(vf, pf[0], acc[0][dt]);
      acc[1][dt] = mfma16(vf, pf[1], acc[1][dt]);
    }
    __builtin_amdgcn_s_setprio(0);

    // B1: all waves' K(t+1) landed (V(t+1) may remain in flight)
    if (pre) BAR_VMCNT4();
  }

  // partial write
  f16* Pp = P + (size_t)sp * PSTRIDE;
#pragma unroll
  for (int qs = 0; qs < 2; ++qs) {
    float l = lsum[qs];
    l += __shfl_xor(l, 16, 64);
    l += __shfl_xor(l, 32, 64);
    int qrow = qrow0 + qs * 16;
    f16* prow = Pp + (size_t)qrow * HDIM;
#pragma unroll
    for (int dt = 0; dt < 16; ++dt) {
      f32x4 a = acc[qs][dt];
      f16x4 h = {(f16)a[0], (f16)a[1], (f16)a[2], (f16)a[3]};
      *(f16x4*)(prow + dt * 16 + 4 * lg) = h;
    }
    if (lane < 16) ml[sp * 16384 + qrow] = l;
  }

  // fused combine: last-arriving sp block normalizes this (b,qb) stripe
  __syncthreads();                  // all stores issued + drained (vmcnt0)
  int* flag = (int*)smem;
  if (tid == 0) {
    __threadfence();                // release: flush partials device-wide
    int old = atomicAdd(&cnt[b * 32 + qb], 1);
    *flag = (old == nsplit - 1) ? 1 : 0;
  }
  __syncthreads();
  if (*flag) {
    __threadfence();                // acquire: invalidate stale cached lines
    size_t base = ((size_t)(b * 4096 + qb * 128)) * 256;
    for (int k = 0; k < 16; ++k) {
      int ci = k * 256 + tid;       // 4096 chunks of 8 elems
      int qrow = b * 4096 + qb * 128 + (ci >> 5);
      size_t off = base + (size_t)ci * 8;
      float l = 0.f;
      float o[8] = {0.f, 0.f, 0.f, 0.f, 0.f, 0.f, 0.f, 0.f};
      for (int sp2 = 0; sp2 < nsplit; ++sp2) {
        l += ml[sp2 * 16384 + qrow];
        f16x8 v = *(const f16x8*)(P + sp2 * PSTRIDE + off);
#pragma unroll
        for (int j = 0; j < 8; ++j) o[j] += (float)v[j];
      }
      float inv = 1.0f / l;
      f32x4 o0 = {o[0] * inv, o[1] * inv, o[2] * inv, o[3] * inv};
      f32x4 o1 = {o[4] * inv, o[5] * inv, o[6] * inv, o[7] * inv};
      *(f32x4*)(out + off) = o0;
      *(f32x4*)(out + off + 4) = o1;
    }
  }
}

// ---------------------------------------------------------------------------
extern "C" void kernel_launch(void* const* d_in, const int* in_sizes, int n_in,
                              void* d_out, int out_size, void* d_ws, size_t ws_size,
                              hipStream_t stream) {
  (void)in_sizes; (void)n_in; (void)out_size;
  const float* x  = (const float*)d_in[0];
  const float* Wq = (const float*)d_in[1];
  const float* bq = (const float*)d_in[2];
  const float* Wk = (const float*)d_in[3];
  const float* bk = (const float*)d_in[4];
  const float* Wv = (const float*)d_in[5];
  const float* bv = (const float*)d_in[6];

  char* ws = (char*)d_ws;
  bf16*  Qb  = (bf16*)(ws);                               // 8 MB [16384][256]
  char*  KV  = ws + (8u << 20);                           // 16 MB [4][128][32KB]
  bf16*  WT  = (bf16*)(ws + (24u << 20));                 // 384 KB
  float* ml  = (float*)(ws + (24u << 20) + (512u << 10)); // 256 KB
  int*   cnt = (int*)(ws + (25u << 20));                  // 512 B counters
  f16*   P   = (f16*)(ws + (26u << 20));                  // nsplit x 8 MB fp16

  size_t need4 = ((size_t)26 << 20) + 4 * ((size_t)8 << 20);
  size_t need2 = ((size_t)26 << 20) + 2 * ((size_t)8 << 20);
  int nsplit = (ws_size >= need4) ? 4 : (ws_size >= need2) ? 2 : 1;
  int ntiles = (S_LEN / nsplit) / 32;
  int nblocks = 128 * nsplit;

  hipMemsetAsync(cnt, 0, 512, stream);
  wt_kernel<<<192, 256, 0, stream>>>(Wq, Wk, Wv, WT);
  proj_kernel<<<dim3(256, 3), 256, 0, stream>>>(x, WT, bq, bk, bv, Qb, KV);
  attn_kernel<<<nblocks, 256, 0, stream>>>(Qb, KV, P, ml, (float*)d_out,
                                           cnt, nsplit, ntiles);
}

// Round 8
// 109.512 us; speedup vs baseline: 1.4936x; 1.4936x over previous
//
#include <hip/hip_runtime.h>
#include <hip/hip_bf16.h>
#include <stdint.h>
#include <stddef.h>

// ---------------------------------------------------------------------------
// TimeSeriesAttention: out = softmax((x Wq + bq)(x Wk + bk)^T / 16) (x Wv + bv)
// B=4, S=4096, H=256, fp32 in/out. bf16 MFMA path.
// v8: v6 skeleton (separate combine kernel — NO device fences; r7 showed
//     threadfence L2-invalidate killed KV residency) + v7's counted-vmcnt
//     dual-barrier attn K-loop as the single A/B variable vs v6's 74.2us.
// ---------------------------------------------------------------------------

typedef __bf16 bf16;
typedef _Float16 f16;
typedef __attribute__((ext_vector_type(4))) __bf16 bf16x4;
typedef __attribute__((ext_vector_type(8))) __bf16 bf16x8;
typedef __attribute__((ext_vector_type(4))) float f32x4;
typedef __attribute__((ext_vector_type(4))) _Float16 f16x4;
typedef __attribute__((ext_vector_type(8))) _Float16 f16x8;

#define S_LEN 4096
#define HDIM  256
#define PSTRIDE ((size_t)16384 * 256)   // elems per fp16 partial buffer (8MB)

__device__ __forceinline__ f32x4 mfma16(bf16x8 a, bf16x8 b, f32x4 c) {
  return __builtin_amdgcn_mfma_f32_16x16x32_bf16(a, b, c, 0, 0, 0);
}

__device__ __forceinline__ void gld_lds16(const void* g, void* l) {
  __builtin_amdgcn_global_load_lds(
      (const __attribute__((address_space(1))) void*)g,
      (__attribute__((address_space(3))) void*)l, 16, 0, 0);
}

__device__ __forceinline__ float fast_exp2(float x) {
  float r;
  asm("v_exp_f32 %0, %1" : "=v"(r) : "v"(x));
  return r;
}

// barrier with counted vmcnt; pinned against IR/scheduler motion
#define BAR_VMCNT4() do { \
  asm volatile("s_waitcnt vmcnt(4)" ::: "memory"); \
  __builtin_amdgcn_s_barrier(); \
  asm volatile("" ::: "memory"); \
  __builtin_amdgcn_sched_barrier(0); } while (0)
#define BAR_VMCNT0() do { \
  asm volatile("s_waitcnt vmcnt(0)" ::: "memory"); \
  __builtin_amdgcn_s_barrier(); \
  asm volatile("" ::: "memory"); \
  __builtin_amdgcn_sched_barrier(0); } while (0)

// ---------------------------------------------------------------------------
// Kernel 1: WT_m[d][h] = (bf16) W_m[h][d].  192 blocks = 3 m x 64 (32x32) tiles.
// ---------------------------------------------------------------------------
__global__ __launch_bounds__(256) void wt_kernel(
    const float* __restrict__ Wq, const float* __restrict__ Wk,
    const float* __restrict__ Wv, bf16* __restrict__ WT) {
  __shared__ float tile[32][33];
  int bid = blockIdx.x;
  int m = bid >> 6;
  int t = bid & 63;
  int hb = (t >> 3) * 32;
  int db = (t & 7) * 32;
  const float* W = (m == 0) ? Wq : (m == 1) ? Wk : Wv;
  bf16* o = WT + m * 65536;
  int ty = threadIdx.x >> 3;
  int tx = threadIdx.x & 7;
  float4 v = *(const float4*)(W + (size_t)(hb + ty) * 256 + db + tx * 4);
  tile[ty][tx * 4 + 0] = v.x; tile[ty][tx * 4 + 1] = v.y;
  tile[ty][tx * 4 + 2] = v.z; tile[ty][tx * 4 + 3] = v.w;
  __syncthreads();
  bf16x4 h = {(bf16)tile[tx * 4 + 0][ty], (bf16)tile[tx * 4 + 1][ty],
              (bf16)tile[tx * 4 + 2][ty], (bf16)tile[tx * 4 + 3][ty]};
  *(bf16x4*)(o + (size_t)(db + ty) * 256 + hb + tx * 4) = h;
}

// ---------------------------------------------------------------------------
// Kernel 2: fused QKV projection (v6 structure, unchanged).
// ---------------------------------------------------------------------------
__global__ __launch_bounds__(256, 3) void proj_kernel(
    const float* __restrict__ x, const bf16* __restrict__ WT,
    const float* __restrict__ bq, const float* __restrict__ bk,
    const float* __restrict__ bv,
    bf16* __restrict__ Qb, char* __restrict__ KV) {
  __shared__ __align__(16) char smem[34816];
  int tid = threadIdx.x;
  int row0 = blockIdx.x * 64;
  int m = blockIdx.y;

#pragma unroll
  for (int i = 0; i < 16; ++i) {
    int c = i * 256 + tid;
    int r = c >> 6, c4 = c & 63;
    float4 v = *(const float4*)(x + (size_t)(row0 + r) * 256 + c4 * 4);
    bf16x4 b4 = {(bf16)v.x, (bf16)v.y, (bf16)v.z, (bf16)v.w};
    *(bf16x4*)(smem + r * 512 + ((c4 * 8) ^ ((r & 7) << 4))) = b4;
  }
  __syncthreads();

  int w = tid >> 6, lane = tid & 63, lg = lane >> 4, l15 = lane & 15;
  int ar = w * 16 + l15;
  int swz = (l15 & 7) << 4;
  bf16x8 af[8];
#pragma unroll
  for (int ks = 0; ks < 8; ++ks)
    af[ks] = *(const bf16x8*)(smem + ar * 512 + ((ks * 64 + lg * 16) ^ swz));
  __syncthreads();

  int b = row0 >> 12, t0 = (row0 & 4095) >> 5;
  const bf16* Wm = WT + m * 65536;
  const float* bias = (m == 0) ? bq : (m == 1) ? bk : bv;

#pragma unroll
  for (int i = 0; i < 4; ++i) {
    int c = w * 4 + i;
    gld_lds16(Wm + (c * 16 + l15) * 256 + lg * 8, smem + c * 1024 + lane * 16);
  }
  __syncthreads();

  f32x4 acc[16];
#pragma unroll
  for (int dt = 0; dt < 16; ++dt) acc[dt] = f32x4{0.f, 0.f, 0.f, 0.f};

  for (int ks = 0; ks < 8; ++ks) {
    const char* wb = smem + (ks & 1) * 16384;
    if (ks + 1 < 8) {
      char* wn = smem + ((ks + 1) & 1) * 16384;
#pragma unroll
      for (int i = 0; i < 4; ++i) {
        int c = w * 4 + i;
        gld_lds16(Wm + (c * 16 + l15) * 256 + (ks + 1) * 32 + lg * 8,
                  wn + c * 1024 + lane * 16);
      }
    }
    __builtin_amdgcn_s_setprio(1);
#pragma unroll
    for (int dt = 0; dt < 16; ++dt) {
      bf16x8 wf = *(const bf16x8*)(wb + dt * 1024 + lane * 16);
      acc[dt] = mfma16(af[ks], wf, acc[dt]);
    }
    __builtin_amdgcn_s_setprio(0);
    __syncthreads();
  }

  if (m == 0) {
#pragma unroll
    for (int dt = 0; dt < 16; ++dt) {
      float bb = bias[dt * 16 + l15];
#pragma unroll
      for (int rr = 0; rr < 4; ++rr) {
        int srow = row0 + w * 16 + 4 * lg + rr;
        Qb[(size_t)srow * 256 + dt * 16 + l15] = (bf16)(acc[dt][rr] + bb);
      }
    }
  } else if (m == 1) {
    bf16* sm16 = (bf16*)smem;
#pragma unroll
    for (int dt = 0; dt < 16; ++dt) {
      float bb = bias[dt * 16 + l15];
#pragma unroll
      for (int rr = 0; rr < 4; ++rr) {
        int sl = w * 16 + 4 * lg + rr;
        sm16[sl * 264 + dt * 16 + l15] = (bf16)(acc[dt][rr] + bb);
      }
    }
    __syncthreads();
    int tt = tid >> 7, c = (tid >> 3) & 15, j0 = (tid & 7) * 8;
    char* dst = KV + ((size_t)(b * 128 + t0 + tt)) * 32768 + c * 1024 + j0 * 16;
#pragma unroll
    for (int u = 0; u < 8; ++u) {
      int l = j0 + u;
      bf16x8 v8 = *(const bf16x8*)(sm16 + (tt * 32 + (c & 1) * 16 + (l & 15)) * 264
                                   + (c >> 1) * 32 + (l >> 4) * 8);
      *(bf16x8*)(dst + u * 16) = v8;
    }
  } else {
    bf16* smV = (bf16*)smem;
#pragma unroll
    for (int dt = 0; dt < 16; ++dt) {
      float bb = bias[dt * 16 + l15];
      bf16x4 h = {(bf16)(acc[dt][0] + bb), (bf16)(acc[dt][1] + bb),
                  (bf16)(acc[dt][2] + bb), (bf16)(acc[dt][3] + bb)};
      *(bf16x4*)(smV + (dt * 16 + l15) * 68 + w * 16 + 4 * lg) = h;
    }
    __syncthreads();
    int tt = tid >> 7, c = (tid >> 3) & 15, j0 = (tid & 7) * 8;
    char* dst = KV + ((size_t)(b * 128 + t0 + tt)) * 32768 + 16384
                + c * 1024 + j0 * 16;
#pragma unroll
    for (int u = 0; u < 8; ++u) {
      int l = j0 + u;
      const bf16* p = smV + (c * 16 + (l & 15)) * 68 + tt * 32 + 4 * (l >> 4);
      bf16x4 lo = *(const bf16x4*)p;
      bf16x4 hi = *(const bf16x4*)(p + 16);
      bf16x8 v8 = __builtin_shufflevector(lo, hi, 0, 1, 2, 3, 4, 5, 6, 7);
      *(bf16x8*)(dst + u * 16) = v8;
    }
  }
}

// ---------------------------------------------------------------------------
// Kernel 3: flash attention. 4 waves x 32 q (QBLK=128), KVBLK=32,
//   counted-vmcnt dual-barrier double-buffer (loads in flight across
//   barriers, never drain to 0 mid-loop). fp16 partials + f32 l.
// ---------------------------------------------------------------------------
__global__ __launch_bounds__(256, 2) void attn_kernel(
    const bf16* __restrict__ Qb, const char* __restrict__ KV,
    f16* __restrict__ P, float* __restrict__ ml, int nsplit, int ntiles) {
  __shared__ __align__(16) char smem[65536];  // 2 bufs x (K 16KB | V 16KB)

  int id = blockIdx.x;
  int b, sp, qb;
  if (nsplit == 4)      { int g = id & 15; b = g & 3;  sp = g >> 2; qb = id >> 4; }
  else if (nsplit == 2) { int g = id & 7;  b = g >> 1; sp = g & 1;  qb = id >> 3; }
  else                  { b = id & 3; sp = 0; qb = id >> 2; }

  int tid = threadIdx.x;
  int w = tid >> 6, lane = tid & 63, lg = lane >> 4, l15 = lane & 15;

  const char* kvsrc = KV + ((size_t)(b * 128 + sp * ntiles)) * 32768;

  // Q fragments: q = qb*128 + w*32 + qs*16 + l15
  int qrow0 = b * S_LEN + qb * 128 + w * 32 + l15;
  bf16x8 qf[2][8];
#pragma unroll
  for (int qs = 0; qs < 2; ++qs) {
    const bf16* Qr = Qb + (size_t)(qrow0 + qs * 16) * HDIM;
#pragma unroll
    for (int ks = 0; ks < 8; ++ks)
      qf[qs][ks] = *(const bf16x8*)(Qr + ks * 32 + lg * 8);
  }

  f32x4 acc[2][16];
#pragma unroll
  for (int qs = 0; qs < 2; ++qs)
#pragma unroll
    for (int dt = 0; dt < 16; ++dt) acc[qs][dt] = f32x4{0.f, 0.f, 0.f, 0.f};
  float lsum[2] = {0.f, 0.f};
  const float C = 0.09016844005556021f;  // (1/16) * log2(e)

  // prologue: stage K(0)+V(0) -> buf 0, full drain once
#pragma unroll
  for (int i = 0; i < 8; ++i)
    gld_lds16(kvsrc + i * 4096 + tid * 16, smem + i * 4096 + tid * 16);
  BAR_VMCNT0();

  for (int t = 0; t < ntiles; ++t) {
    int cur = (t & 1) << 15;
    const char* kb = smem + cur;
    const char* vb = kb + 16384;
    const char* s2 = kvsrc + (size_t)(t + 1) * 32768;
    char* d2 = smem + (cur ^ 32768);
    bool pre = (t + 1 < ntiles);

    if (pre) {                      // issue K(t+1): stays in flight across B2
#pragma unroll
      for (int i = 0; i < 4; ++i)
        gld_lds16(s2 + i * 4096 + tid * 16, d2 + i * 4096 + tid * 16);
    }

    // S^T = K . Q^T (reads K(t); safe per B1 of t-1 / prologue)
    f32x4 st[2][2];
    st[0][0] = f32x4{0.f, 0.f, 0.f, 0.f}; st[0][1] = st[0][0];
    st[1][0] = st[0][0];                   st[1][1] = st[0][0];
    __builtin_amdgcn_s_setprio(1);
#pragma unroll
    for (int ks = 0; ks < 8; ++ks) {
      bf16x8 k0 = *(const bf16x8*)(kb + (ks * 2 + 0) * 1024 + lane * 16);
      bf16x8 k1 = *(const bf16x8*)(kb + (ks * 2 + 1) * 1024 + lane * 16);
      st[0][0] = mfma16(k0, qf[0][ks], st[0][0]);
      st[1][0] = mfma16(k0, qf[1][ks], st[1][0]);
      st[0][1] = mfma16(k1, qf[0][ks], st[0][1]);
      st[1][1] = mfma16(k1, qf[1][ks], st[1][1]);
    }
    __builtin_amdgcn_s_setprio(0);

    // B2: all waves' V(t) landed (K(t+1) may remain in flight)
    if (pre) BAR_VMCNT4(); else BAR_VMCNT0();

    if (pre) {                      // issue V(t+1): in flight across B1
#pragma unroll
      for (int i = 4; i < 8; ++i)
        gld_lds16(s2 + i * 4096 + tid * 16, d2 + i * 4096 + tid * 16);
    }

    // no-max softmax
    bf16x8 pf[2];
#pragma unroll
    for (int qs = 0; qs < 2; ++qs) {
      float ps = 0.f;
#pragma unroll
      for (int e = 0; e < 8; ++e) {
        float pv = fast_exp2(st[qs][e >> 2][e & 3] * C);
        ps += pv;
        pf[qs][e] = (bf16)pv;   // kv = 16*(e>>2) + 4*lg + (e&3)
      }
      lsum[qs] += ps;
    }

    // O^T += V^T . P^T (reads V(t); safe per B2)
    __builtin_amdgcn_s_setprio(1);
#pragma unroll
    for (int dt = 0; dt < 16; ++dt) {
      bf16x8 vf = *(const bf16x8*)(vb + dt * 1024 + lane * 16);
      acc[0][dt] = mfma16(vf, pf[0], acc[0][dt]);
      acc[1][dt] = mfma16(vf, pf[1], acc[1][dt]);
    }
    __builtin_amdgcn_s_setprio(0);

    // B1: all waves' K(t+1) landed (V(t+1) may remain in flight)
    if (pre) BAR_VMCNT4();
  }

  f16* Pp = P + (size_t)sp * PSTRIDE;
#pragma unroll
  for (int qs = 0; qs < 2; ++qs) {
    float l = lsum[qs];
    l += __shfl_xor(l, 16, 64);
    l += __shfl_xor(l, 32, 64);
    int qrow = qrow0 + qs * 16;
    f16* prow = Pp + (size_t)qrow * HDIM;
#pragma unroll
    for (int dt = 0; dt < 16; ++dt) {
      f32x4 a = acc[qs][dt];
      f16x4 h = {(f16)a[0], (f16)a[1], (f16)a[2], (f16)a[3]};
      *(f16x4*)(prow + dt * 16 + 4 * lg) = h;
    }
    if (lane < 16) ml[sp * 16384 + qrow] = l;
  }
}

// ---------------------------------------------------------------------------
// Kernel 4: combine fp16 partials + normalize -> f32 d_out
// ---------------------------------------------------------------------------
__global__ __launch_bounds__(256) void combine_kernel(
    float* __restrict__ out, const f16* __restrict__ P,
    const float* __restrict__ ml, int nsplit) {
  int chunk = blockIdx.x * 256 + threadIdx.x;  // 524288 chunks of 8 elems
  int q = chunk >> 5;
  size_t base = (size_t)chunk * 8;

  float l = 0.f;
  float o[8] = {0.f, 0.f, 0.f, 0.f, 0.f, 0.f, 0.f, 0.f};
  for (int sp = 0; sp < nsplit; ++sp) {
    l += ml[sp * 16384 + q];
    f16x8 v = *(const f16x8*)(P + sp * PSTRIDE + base);
#pragma unroll
    for (int j = 0; j < 8; ++j) o[j] += (float)v[j];
  }
  float inv = 1.0f / l;
  f32x4 o0 = {o[0] * inv, o[1] * inv, o[2] * inv, o[3] * inv};
  f32x4 o1 = {o[4] * inv, o[5] * inv, o[6] * inv, o[7] * inv};
  *(f32x4*)(out + base) = o0;
  *(f32x4*)(out + base + 4) = o1;
}

// ---------------------------------------------------------------------------
extern "C" void kernel_launch(void* const* d_in, const int* in_sizes, int n_in,
                              void* d_out, int out_size, void* d_ws, size_t ws_size,
                              hipStream_t stream) {
  (void)in_sizes; (void)n_in; (void)out_size;
  const float* x  = (const float*)d_in[0];
  const float* Wq = (const float*)d_in[1];
  const float* bq = (const float*)d_in[2];
  const float* Wk = (const float*)d_in[3];
  const float* bk = (const float*)d_in[4];
  const float* Wv = (const float*)d_in[5];
  const float* bv = (const float*)d_in[6];

  char* ws = (char*)d_ws;
  bf16*  Qb = (bf16*)(ws);                               // 8 MB [16384][256]
  char*  KV = ws + (8u << 20);                           // 16 MB [4][128][32KB]
  bf16*  WT = (bf16*)(ws + (24u << 20));                 // 384 KB
  float* ml = (float*)(ws + (24u << 20) + (512u << 10)); // 256 KB
  f16*   P  = (f16*)(ws + (26u << 20));                  // nsplit x 8 MB fp16

  size_t need4 = ((size_t)26 << 20) + 4 * ((size_t)8 << 20);
  size_t need2 = ((size_t)26 << 20) + 2 * ((size_t)8 << 20);
  int nsplit = (ws_size >= need4) ? 4 : (ws_size >= need2) ? 2 : 1;
  int ntiles = (S_LEN / nsplit) / 32;
  int nblocks = 128 * nsplit;

  wt_kernel<<<192, 256, 0, stream>>>(Wq, Wk, Wv, WT);
  proj_kernel<<<dim3(256, 3), 256, 0, stream>>>(x, WT, bq, bk, bv, Qb, KV);
  attn_kernel<<<nblocks, 256, 0, stream>>>(Qb, KV, P, ml, nsplit, ntiles);
  combine_kernel<<<2048, 256, 0, stream>>>((float*)d_out, P, ml, nsplit);
}